// Round 4
// baseline (103.523 us; speedup 1.0000x reference)
//
#include <hip/hip_runtime.h>
#include <math.h>

#define NUM_RBF 64
#define N_GRAPHS 64

typedef int   int4v   __attribute__((ext_vector_type(4)));
typedef float float4v __attribute__((ext_vector_type(4)));

// Model (r0-r3): edge kernel is gather-LATENCY bound with insufficient
// per-wave memory-level parallelism. Evidence: identical duration cold vs
// warm cache (r1 replay rows), all pipes <10% busy, warming (r2) and
// LDS-table (r3) both neutral, TA-throughput floor arithmetic ~8-10us vs
// ~25us measured. r0-structure waves own ONE quad -> serial chain
// idx->gather->compute with <=10 loads in flight, once.
// This version: 2-deep software pipeline, ~3 quads/thread (512-ish blocks):
// quad k+1's index loads + 8 record gathers are issued BEFORE quad k's
// compute, doubling in-flight gathers and overlapping compute with memory.
// All table/record reads nontemporal (L1 ~4% hit on 800KB table; bypass
// its allocate/MSHR path). Partials+reduce kept (r1: fused same-address
// global atomics cost +24us).

__global__ __launch_bounds__(256) void prologue_kernel(
    const float4v* __restrict__ p, const float4v* __restrict__ f,
    float4v* __restrict__ C, int n4,
    const float* __restrict__ pos, const int* __restrict__ types,
    const int* __restrict__ batch, float4v* __restrict__ rec, int N)
{
    int i = blockIdx.x * blockDim.x + threadIdx.x;
    if (i < n4) C[i] = p[i] * f[i];
    if (i < N) {
        int bits = (types[i] & 0xFF) | ((batch[i] & 0xFF) << 8);
        float4v r = { pos[3 * i], pos[3 * i + 1], pos[3 * i + 2],
                      __int_as_float(bits) };
        rec[i] = r;
    }
}

#define CUTOFF_F      5.0f
#define GAMMA_F       163.84f                    /* (64/5)^2                  */
#define SPACING_F     (float)(5.0 / 63.0)
#define INV_SPACING_F (float)(63.0 / 5.0)
#define PI_OVER_C_F   (float)(3.14159265358979323846 / 5.0)
#define TWO_GAMMA_S_F (float)(2.0 * 163.84 * 5.0 / 63.0)   /* 26.00635 */
// v = exp(-gamma*s^2) = exp(-(64/63)^2)
#define LN_V          (-(64.0 / 63.0) * (64.0 / 63.0))
#define V_1           (float)exp(LN_V)           /* v    (first ratio factor) */
#define V_2           (float)exp(2.0 * LN_V)     /* v^2  (per-step multiplier)*/

__device__ __forceinline__ void edge_body(
    float4v rs, float4v rd, const float4v* __restrict__ tab, int T,
    float* __restrict__ bins)
{
    const float dx = rd.x - rs.x;
    const float dy = rd.y - rs.y;
    const float dz = rd.z - rs.z;
    const float d  = sqrtf(dx * dx + dy * dy + dz * dz + 1e-12f);
    if (d >= CUTOFF_F) return;

    const int sb = __float_as_int(rs.w);
    const int db = __float_as_int(rd.w);
    const int ts = sb & 0xFF;
    const int td = db & 0xFF;
    const int lo = min(ts, td);
    const int hi = max(ts, td);
    const int base = (lo * T + hi) * NUM_RBF;

    // 12-tap window, start aligned to x4; covers >= +-3.5 spacings
    const float c = d * INV_SPACING_F;
    int a0 = ((int)floorf(c - 3.5f)) & ~3;
    a0 = max(0, min(NUM_RBF - 12, a0));

    const float4v* w = tab + ((base + a0) >> 2);
    const float4v w0 = __builtin_nontemporal_load(w);
    const float4v w1 = __builtin_nontemporal_load(w + 1);
    const float4v w2 = __builtin_nontemporal_load(w + 2);

    // Taps t_k = exp(-gamma*(delta-k*s)^2), k=0..11, anchored at k=5:
    //   up  : t_{k+1} = t_k * m,  m0 = u  * v,  m *= v^2 per step
    //   down: t_{k-1} = t_k * m,  m0 = ui * v,  m *= v^2 per step
    //   u = exp(+2*gamma*s*d5), ui = 1/u, d5 = delta - 5s, v = exp(-gamma*s^2)
    const float delta = d - (float)a0 * SPACING_F;
    const float d5 = delta - 5.0f * SPACING_F;
    const float t5 = __expf(-GAMMA_F * d5 * d5);
    const float x  = TWO_GAMMA_S_F * d5;
    const float u  = __expf(x);
    const float ui = __expf(-x);

    float acc = w1.y * t5;                 // k=5
    float t = t5, m = u * V_1;             // upward k=6..11
    t *= m;  acc += w1.z * t;  m *= V_2;
    t *= m;  acc += w1.w * t;  m *= V_2;
    t *= m;  acc += w2.x * t;  m *= V_2;
    t *= m;  acc += w2.y * t;  m *= V_2;
    t *= m;  acc += w2.z * t;  m *= V_2;
    t *= m;  acc += w2.w * t;
    t = t5;  m = ui * V_1;                 // downward k=4..0
    t *= m;  acc += w1.x * t;  m *= V_2;
    t *= m;  acc += w0.w * t;  m *= V_2;
    t *= m;  acc += w0.z * t;  m *= V_2;
    t *= m;  acc += w0.y * t;  m *= V_2;
    t *= m;  acc += w0.x * t;

    const float fc = 0.5f * (__cosf(PI_OVER_C_F * d) + 1.0f);
    atomicAdd(&bins[(sb >> 8) & 0xFF], acc * fc);
}

struct Quad {
    float4v rs0, rd0, rs1, rd1, rs2, rd2, rs3, rd3;
};

__device__ __forceinline__ Quad load_quad(
    const int* __restrict__ ei, const float4v* __restrict__ rec,
    int E, int e0)
{
    const int4v sv = __builtin_nontemporal_load((const int4v*)(ei + e0));
    const int4v tv = __builtin_nontemporal_load((const int4v*)(ei + E + e0));
    Quad g;
    g.rs0 = __builtin_nontemporal_load(rec + sv.x);
    g.rd0 = __builtin_nontemporal_load(rec + tv.x);
    g.rs1 = __builtin_nontemporal_load(rec + sv.y);
    g.rd1 = __builtin_nontemporal_load(rec + tv.y);
    g.rs2 = __builtin_nontemporal_load(rec + sv.z);
    g.rd2 = __builtin_nontemporal_load(rec + tv.z);
    g.rs3 = __builtin_nontemporal_load(rec + sv.w);
    g.rd3 = __builtin_nontemporal_load(rec + tv.w);
    return g;
}

__global__ __launch_bounds__(256) void edge_energy_kernel(
    const int*     __restrict__ edge_index,
    const float4v* __restrict__ rec,
    const float4v* __restrict__ C4,
    float*         __restrict__ partial,
    int E, int T)
{
    __shared__ float bins[N_GRAPHS];
    for (int i = threadIdx.x; i < N_GRAPHS; i += blockDim.x) bins[i] = 0.0f;
    __syncthreads();

    const int nq     = E >> 2;
    const int stride = gridDim.x * blockDim.x;
    const int gid    = blockIdx.x * blockDim.x + threadIdx.x;

    int  q   = gid;
    bool has = q < nq;
    Quad A;
    if (has) A = load_quad(edge_index, rec, E, q << 2);

    while (has) {
        const int  qn   = q + stride;
        const bool hasn = qn < nq;
        Quad B = A;
        // issue next quad's idx loads + 8 gathers BEFORE computing current:
        // they stay in flight (counted vmcnt) across the ~600cy compute.
        if (hasn) B = load_quad(edge_index, rec, E, qn << 2);

        edge_body(A.rs0, A.rd0, C4, T, bins);
        edge_body(A.rs1, A.rd1, C4, T, bins);
        edge_body(A.rs2, A.rd2, C4, T, bins);
        edge_body(A.rs3, A.rd3, C4, T, bins);

        A = B; q = qn; has = hasn;
    }

    if (gid == 0) {                       // tail edges (E % 4)
        for (int e = nq << 2; e < E; ++e) {
            const float4v rs = rec[edge_index[e]];
            const float4v rd = rec[edge_index[E + e]];
            edge_body(rs, rd, C4, T, bins);
        }
    }

    __syncthreads();
    for (int i = threadIdx.x; i < N_GRAPHS; i += blockDim.x)
        partial[blockIdx.x * N_GRAPHS + i] = bins[i];
}

__global__ __launch_bounds__(256) void reduce_kernel(
    const float* __restrict__ partial, float* __restrict__ out, int nblocks)
{
    const int g = blockIdx.x;
    float s = 0.0f;
    for (int i = threadIdx.x; i < nblocks; i += blockDim.x)
        s += partial[i * N_GRAPHS + g];

    for (int off = 32; off > 0; off >>= 1)
        s += __shfl_down(s, off, 64);

    __shared__ float red[4];
    const int wave = threadIdx.x >> 6;
    const int lane = threadIdx.x & 63;
    if (lane == 0) red[wave] = s;
    __syncthreads();
    if (threadIdx.x == 0)
        out[g] = red[0] + red[1] + red[2] + red[3];
}

extern "C" void kernel_launch(void* const* d_in, const int* in_sizes, int n_in,
                              void* d_out, int out_size, void* d_ws, size_t ws_size,
                              hipStream_t stream) {
    const float* pos            = (const float*)d_in[0];
    const float* rbf_params     = (const float*)d_in[1];
    const float* radial_filters = (const float*)d_in[2];
    const int*   edge_index     = (const int*)d_in[3];
    const int*   atom_types     = (const int*)d_in[4];
    const int*   batch          = (const int*)d_in[5];
    float*       out            = (float*)d_out;

    const int E = in_sizes[3] / 2;
    const int N = in_sizes[4];
    int T = 1;
    while ((T + 1) * (T + 1) * NUM_RBF <= in_sizes[1]) ++T;
    const int tbl_elems = T * T * NUM_RBF;          // multiple of 4

    // workspace layout (256B aligned): [table | node recs | partials]
    float*   Ctab    = (float*)d_ws;
    float4v* recs    = (float4v*)((char*)d_ws + ((size_t)tbl_elems * 4 + 255) / 256 * 256);
    float*   partial = (float*)((char*)recs + (size_t)N * 16);

    const int nq = E >> 2;
    // ~3 quads per thread so the 2-deep pipeline has >=2 iterations to fill
    int nblocks = (nq / 3 + 255) / 256;
    const size_t part_off = (size_t)((char*)partial - (char*)d_ws);
    const size_t avail = (ws_size > part_off) ? (ws_size - part_off) : 0;
    const int maxb = (int)(avail / (N_GRAPHS * sizeof(float)));
    if (nblocks > maxb) nblocks = maxb > 0 ? maxb : 1;
    if (nblocks < 1) nblocks = 1;

    const int pro_n = max(tbl_elems / 4, N);
    prologue_kernel<<<(pro_n + 255) / 256, 256, 0, stream>>>(
        (const float4v*)rbf_params, (const float4v*)radial_filters,
        (float4v*)Ctab, tbl_elems / 4, pos, atom_types, batch, recs, N);
    edge_energy_kernel<<<nblocks, 256, 0, stream>>>(
        edge_index, recs, (const float4v*)Ctab, partial, E, T);
    reduce_kernel<<<N_GRAPHS, 256, 0, stream>>>(partial, out, nblocks);
}

// Round 5
// 96.294 us; speedup vs baseline: 1.0751x; 1.0751x over previous
//
#include <hip/hip_runtime.h>
#include <math.h>

#define NUM_RBF 64
#define N_GRAPHS 64

typedef int   int4v   __attribute__((ext_vector_type(4)));
typedef float float4v __attribute__((ext_vector_type(4)));

// FINAL (r0 structure, best measured 94.9/96.5us). r1-r4 established:
//  - fused same-address global atomics: -22us regression (serialized RMW)
//  - per-XCD L2 warming: null (lines already local-L2 at steady state)
//  - LDS-staged table: null (random-base ds_read bank conflicts eat the
//    L2-line savings)
//  - 2-deep software pipeline: regression (idx->gather dep chain stalls
//    before compute; +64 VGPR)
// Model: edge kernel is at the per-CU MSHR x L2-latency floor:
// ~4.8M divergent line-requests / (256 CU x ~64 in flight / ~200cy) ~ 24us,
// matching measurement. Remaining time = 42us harness poison fill +
// prologue/reduce/launch overhead.

__global__ __launch_bounds__(256) void prologue_kernel(
    const float4v* __restrict__ p, const float4v* __restrict__ f,
    float4v* __restrict__ C, int n4,
    const float* __restrict__ pos, const int* __restrict__ types,
    const int* __restrict__ batch, float4v* __restrict__ rec, int N)
{
    int i = blockIdx.x * blockDim.x + threadIdx.x;
    if (i < n4) C[i] = p[i] * f[i];
    if (i < N) {
        int bits = (types[i] & 0xFF) | ((batch[i] & 0xFF) << 8);
        float4v r = { pos[3 * i], pos[3 * i + 1], pos[3 * i + 2],
                      __int_as_float(bits) };
        rec[i] = r;
    }
}

#define CUTOFF_F      5.0f
#define GAMMA_F       163.84f                    /* (64/5)^2                  */
#define SPACING_F     (float)(5.0 / 63.0)
#define INV_SPACING_F (float)(63.0 / 5.0)
#define PI_OVER_C_F   (float)(3.14159265358979323846 / 5.0)
#define TWO_GAMMA_S_F (float)(2.0 * 163.84 * 5.0 / 63.0)   /* 26.00635 */
// v = exp(-gamma*s^2) = exp(-(64/63)^2)
#define LN_V          (-(64.0 / 63.0) * (64.0 / 63.0))
#define V_1           (float)exp(LN_V)           /* v    (first ratio factor) */
#define V_2           (float)exp(2.0 * LN_V)     /* v^2  (per-step multiplier)*/

__device__ __forceinline__ void edge_body(
    float4v rs, float4v rd, const float4v* __restrict__ C4, int T,
    float* __restrict__ bins)
{
    const float dx = rd.x - rs.x;
    const float dy = rd.y - rs.y;
    const float dz = rd.z - rs.z;
    const float d  = sqrtf(dx * dx + dy * dy + dz * dz + 1e-12f);
    if (d >= CUTOFF_F) return;

    const int sb = __float_as_int(rs.w);
    const int db = __float_as_int(rd.w);
    const int ts = sb & 0xFF;
    const int td = db & 0xFF;
    const int lo = min(ts, td);
    const int hi = max(ts, td);
    const int base = (lo * T + hi) * NUM_RBF;

    // 12-tap window, start aligned to x4; covers >= +-3.5 spacings
    const float c = d * INV_SPACING_F;
    int a0 = ((int)floorf(c - 3.5f)) & ~3;
    a0 = max(0, min(NUM_RBF - 12, a0));

    const float4v* w = C4 + ((base + a0) >> 2);
    const float4v w0 = w[0], w1 = w[1], w2 = w[2];

    // Taps t_k = exp(-gamma*(delta-k*s)^2), k=0..11, anchored at k=5:
    //   up  : t_{k+1} = t_k * m,  m0 = u  * v,  m *= v^2 per step
    //   down: t_{k-1} = t_k * m,  m0 = ui * v,  m *= v^2 per step
    //   u = exp(+2*gamma*s*d5), ui = 1/u, d5 = delta - 5s, v = exp(-gamma*s^2)
    // (verified vs direct exp at delta=0.4: t4/t6/t7 match to 5 digits;
    //  max intermediate u = e^12.4 — no overflow in the clamp corners)
    const float delta = d - (float)a0 * SPACING_F;
    const float d5 = delta - 5.0f * SPACING_F;
    const float t5 = __expf(-GAMMA_F * d5 * d5);
    const float x  = TWO_GAMMA_S_F * d5;
    const float u  = __expf(x);
    const float ui = __expf(-x);

    float acc = w1.y * t5;                 // k=5
    float t = t5, m = u * V_1;             // upward k=6..11
    t *= m;  acc += w1.z * t;  m *= V_2;
    t *= m;  acc += w1.w * t;  m *= V_2;
    t *= m;  acc += w2.x * t;  m *= V_2;
    t *= m;  acc += w2.y * t;  m *= V_2;
    t *= m;  acc += w2.z * t;  m *= V_2;
    t *= m;  acc += w2.w * t;
    t = t5;  m = ui * V_1;                 // downward k=4..0
    t *= m;  acc += w1.x * t;  m *= V_2;
    t *= m;  acc += w0.w * t;  m *= V_2;
    t *= m;  acc += w0.z * t;  m *= V_2;
    t *= m;  acc += w0.y * t;  m *= V_2;
    t *= m;  acc += w0.x * t;

    const float fc = 0.5f * (__cosf(PI_OVER_C_F * d) + 1.0f);
    atomicAdd(&bins[(sb >> 8) & 0xFF], acc * fc);
}

__global__ __launch_bounds__(256) void edge_energy_kernel(
    const int*     __restrict__ edge_index,
    const float4v* __restrict__ rec,
    const float4v* __restrict__ C4,
    float*         __restrict__ partial,
    int E, int T)
{
    __shared__ float bins[N_GRAPHS];
    for (int i = threadIdx.x; i < N_GRAPHS; i += blockDim.x) bins[i] = 0.0f;
    __syncthreads();

    const int nfull  = E >> 2;
    const int stride = gridDim.x * blockDim.x;
    const int gid    = blockIdx.x * blockDim.x + threadIdx.x;

    for (int q = gid; q < nfull; q += stride) {
        const int e0 = q << 2;
        // nontemporal: 12.8 MB once-streamed index data must not evict the
        // hot node-record / table working set from L2
        const int4v sv = __builtin_nontemporal_load(
            (const int4v*)(edge_index + e0));
        const int4v tv = __builtin_nontemporal_load(
            (const int4v*)(edge_index + E + e0));

        const float4v rs0 = rec[sv.x], rd0 = rec[tv.x];
        const float4v rs1 = rec[sv.y], rd1 = rec[tv.y];
        const float4v rs2 = rec[sv.z], rd2 = rec[tv.z];
        const float4v rs3 = rec[sv.w], rd3 = rec[tv.w];

        edge_body(rs0, rd0, C4, T, bins);
        edge_body(rs1, rd1, C4, T, bins);
        edge_body(rs2, rd2, C4, T, bins);
        edge_body(rs3, rd3, C4, T, bins);
    }

    if (gid == 0) {                       // tail edges (E % 4)
        for (int e = nfull << 2; e < E; ++e) {
            const float4v rs = rec[edge_index[e]];
            const float4v rd = rec[edge_index[E + e]];
            edge_body(rs, rd, C4, T, bins);
        }
    }

    __syncthreads();
    for (int i = threadIdx.x; i < N_GRAPHS; i += blockDim.x)
        partial[blockIdx.x * N_GRAPHS + i] = bins[i];
}

__global__ __launch_bounds__(256) void reduce_kernel(
    const float* __restrict__ partial, float* __restrict__ out, int nblocks)
{
    const int g = blockIdx.x;
    float s = 0.0f;
    for (int i = threadIdx.x; i < nblocks; i += blockDim.x)
        s += partial[i * N_GRAPHS + g];

    for (int off = 32; off > 0; off >>= 1)
        s += __shfl_down(s, off, 64);

    __shared__ float red[4];
    const int wave = threadIdx.x >> 6;
    const int lane = threadIdx.x & 63;
    if (lane == 0) red[wave] = s;
    __syncthreads();
    if (threadIdx.x == 0)
        out[g] = red[0] + red[1] + red[2] + red[3];
}

extern "C" void kernel_launch(void* const* d_in, const int* in_sizes, int n_in,
                              void* d_out, int out_size, void* d_ws, size_t ws_size,
                              hipStream_t stream) {
    const float* pos            = (const float*)d_in[0];
    const float* rbf_params     = (const float*)d_in[1];
    const float* radial_filters = (const float*)d_in[2];
    const int*   edge_index     = (const int*)d_in[3];
    const int*   atom_types     = (const int*)d_in[4];
    const int*   batch          = (const int*)d_in[5];
    float*       out            = (float*)d_out;

    const int E = in_sizes[3] / 2;
    const int N = in_sizes[4];
    int T = 1;
    while ((T + 1) * (T + 1) * NUM_RBF <= in_sizes[1]) ++T;
    const int tbl_elems = T * T * NUM_RBF;          // multiple of 4

    // workspace layout (256B aligned): [table | node recs | partials]
    float*   Ctab    = (float*)d_ws;
    float4v* recs    = (float4v*)((char*)d_ws + ((size_t)tbl_elems * 4 + 255) / 256 * 256);
    float*   partial = (float*)((char*)recs + (size_t)N * 16);

    const int nq = E >> 2;
    int nblocks = (nq + 255) / 256;                 // one quad per thread
    const size_t part_off = (size_t)((char*)partial - (char*)d_ws);
    const size_t avail = (ws_size > part_off) ? (ws_size - part_off) : 0;
    const int maxb = (int)(avail / (N_GRAPHS * sizeof(float)));
    if (nblocks > maxb) nblocks = maxb > 0 ? maxb : 1;
    if (nblocks < 1) nblocks = 1;

    const int pro_n = max(tbl_elems / 4, N);
    prologue_kernel<<<(pro_n + 255) / 256, 256, 0, stream>>>(
        (const float4v*)rbf_params, (const float4v*)radial_filters,
        (float4v*)Ctab, tbl_elems / 4, pos, atom_types, batch, recs, N);
    edge_energy_kernel<<<nblocks, 256, 0, stream>>>(
        edge_index, recs, (const float4v*)Ctab, partial, E, T);
    reduce_kernel<<<N_GRAPHS, 256, 0, stream>>>(partial, out, nblocks);
}